// Round 4
// baseline (689.160 us; speedup 1.0000x reference)
//
#include <hip/hip_runtime.h>
#include <cstdint>
#include <cmath>

// GCN, 4 layers: h = elu(A_norm (h W) + b) x3, then log_softmax(A_norm (h W4) + b4)
// A_norm = D^-1/2 (A + I) D^-1/2 with edge weights, D from weighted in-degree + self-loop.
//
// Strategy: build CSR by destination once per call (histogram -> scan -> scatter,
// int atomics only), then per layer: fp32 GEMM (W^T staged in LDS, row/thread),
// wave-per-node aggregation (lane = feature, coalesced 256B row gathers, no float
// atomics), ELU fused into aggregation write. Final wave-per-row log_softmax.

#ifndef AGG_UNROLL
#define AGG_UNROLL 4
#endif

// ---------------------------------------------------------------- setup kernels

__global__ __launch_bounds__(256) void init_kernel(float* __restrict__ deg,
                                                   int* __restrict__ cnt, int n) {
    int i = blockIdx.x * 256 + threadIdx.x;
    if (i < n) { deg[i] = 1.0f; cnt[i] = 0; }   // self-loop weight 1 pre-seeded
}

__global__ __launch_bounds__(256) void deg_accum_kernel(const int* __restrict__ dst,
                                                        const float* __restrict__ w,
                                                        float* __restrict__ deg,
                                                        int* __restrict__ cnt, int E) {
    int stride = gridDim.x * 256;
    for (int e = blockIdx.x * 256 + threadIdx.x; e < E; e += stride) {
        int d = dst[e];
        atomicAdd(&deg[d], w[e]);
        atomicAdd(&cnt[d], 1);
    }
}

__global__ __launch_bounds__(256) void dis_kernel(float* __restrict__ deg,
                                                  float* __restrict__ selfnorm, int n) {
    int i = blockIdx.x * 256 + threadIdx.x;
    if (i < n) {
        float d = deg[i];
        float r = (d > 0.f) ? rsqrtf(fmaxf(d, 1e-12f)) : 0.f;
        deg[i] = r;            // deg buffer becomes dis
        selfnorm[i] = r * r;   // self-loop norm: dis*1*dis
    }
}

// single-block hierarchical exclusive scan of cnt[0..n) -> offsets, resets cnt to 0
__global__ __launch_bounds__(1024) void scan_kernel(int* __restrict__ cnt,
                                                    int* __restrict__ offsets, int n) {
    __shared__ int wsum[16];
    __shared__ int sbase;
    int lane = threadIdx.x & 63;
    int wid  = threadIdx.x >> 6;
    if (threadIdx.x == 0) sbase = 0;
    __syncthreads();
    for (int base = 0; base < n; base += 1024) {
        int i = base + (int)threadIdx.x;
        int v = (i < n) ? cnt[i] : 0;
        int x = v;
        #pragma unroll
        for (int off = 1; off < 64; off <<= 1) {
            int t = __shfl_up(x, off);
            if (lane >= off) x += t;
        }
        if (lane == 63) wsum[wid] = x;
        __syncthreads();
        if (threadIdx.x == 0) {
            int acc = sbase;
            #pragma unroll
            for (int wv = 0; wv < 16; ++wv) { int t = wsum[wv]; wsum[wv] = acc; acc += t; }
            sbase = acc;
        }
        __syncthreads();
        if (i < n) { offsets[i] = wsum[wid] + (x - v); cnt[i] = 0; }
        __syncthreads();
    }
    if (threadIdx.x == 0) offsets[n] = sbase;
}

// scatter edges into CSR slots; fuse norm = dis[src]*w*dis[dst]
__global__ __launch_bounds__(256) void scatter_kernel(const int* __restrict__ src,
                                                      const int* __restrict__ dst,
                                                      const float* __restrict__ w,
                                                      const float* __restrict__ dis,
                                                      const int* __restrict__ offsets,
                                                      int* __restrict__ cnt,
                                                      int2* __restrict__ pairs, int E) {
    int stride = gridDim.x * 256;
    for (int e = blockIdx.x * 256 + threadIdx.x; e < E; e += stride) {
        int s = src[e], d = dst[e];
        float nrm = dis[s] * w[e] * dis[d];
        int pos = offsets[d] + atomicAdd(&cnt[d], 1);
        pairs[pos] = make_int2(s, __float_as_int(nrm));
    }
}

// ---------------------------------------------------------------- GEMM: out = in @ W
// in [n][64] fp32, W [64][COUT] fp32 (row-major), out [n][COUT].
// One row per thread; W^T staged in LDS (ds_read_b128 broadcast across lanes).
template <int COUT>
__global__ __launch_bounds__(256) void gemm_kernel(const float* __restrict__ in,
                                                   const float* __restrict__ W,
                                                   float* __restrict__ out, int n) {
    __shared__ float WT[COUT][64];   // WT[c][k] = W[k][c]
    for (int idx = threadIdx.x; idx < 64 * COUT; idx += 256) {
        int k = idx / COUT, c = idx % COUT;
        WT[c][k] = W[idx];
    }
    __syncthreads();

    int row = blockIdx.x * 256 + threadIdx.x;
    if (row >= n) return;

    float4 h[16];
    const float4* inp = reinterpret_cast<const float4*>(in + (size_t)row * 64);
    #pragma unroll
    for (int i = 0; i < 16; ++i) h[i] = inp[i];

    float* outp = out + (size_t)row * COUT;
    #pragma unroll 2
    for (int c4 = 0; c4 < COUT / 4; ++c4) {
        float r[4];
        #pragma unroll
        for (int cc = 0; cc < 4; ++cc) {
            const float4* wt = reinterpret_cast<const float4*>(&WT[c4 * 4 + cc][0]);
            float4 a = make_float4(0.f, 0.f, 0.f, 0.f);
            #pragma unroll
            for (int i = 0; i < 16; ++i) {
                float4 w4 = wt[i];
                a.x = fmaf(h[i].x, w4.x, a.x);
                a.y = fmaf(h[i].y, w4.y, a.y);
                a.z = fmaf(h[i].z, w4.z, a.z);
                a.w = fmaf(h[i].w, w4.w, a.w);
            }
            r[cc] = (a.x + a.y) + (a.z + a.w);
        }
        *reinterpret_cast<float4*>(outp + c4 * 4) = make_float4(r[0], r[1], r[2], r[3]);
    }
}

// ------------------------------------------------------- aggregation (wave per node)
// out[i][f] = act( b[f] + selfnorm[i]*tmp[i][f] + sum_e nrm_e * tmp[src_e][f] )
template <int COUT, bool ELU_ACT>
__global__ __launch_bounds__(256) void aggregate_kernel(const float* __restrict__ tmp,
                                                        const float* __restrict__ selfnorm,
                                                        const int* __restrict__ offsets,
                                                        const int2* __restrict__ pairs,
                                                        const float* __restrict__ bias,
                                                        float* __restrict__ out, int n) {
    int lane = threadIdx.x & 63;
    int node = blockIdx.x * 4 + (threadIdx.x >> 6);
    if (node >= n) return;
    const bool act = (COUT == 64) || (lane < COUT);

    float acc = 0.f;
    if (act) acc = bias[lane] + selfnorm[node] * tmp[(size_t)node * COUT + lane];

    int j = offsets[node];
    int end = offsets[node + 1];

    for (; j + AGG_UNROLL <= end; j += AGG_UNROLL) {
        int2 p[AGG_UNROLL];
        float v[AGG_UNROLL];
        #pragma unroll
        for (int u = 0; u < AGG_UNROLL; ++u) p[u] = pairs[j + u];
        #pragma unroll
        for (int u = 0; u < AGG_UNROLL; ++u)
            v[u] = act ? tmp[(size_t)p[u].x * COUT + lane] : 0.f;
        #pragma unroll
        for (int u = 0; u < AGG_UNROLL; ++u)
            acc = fmaf(__int_as_float(p[u].y), v[u], acc);
    }
    for (; j < end; ++j) {
        int2 p = pairs[j];
        float v = act ? tmp[(size_t)p.x * COUT + lane] : 0.f;
        acc = fmaf(__int_as_float(p.y), v, acc);
    }

    if (act) {
        if (ELU_ACT) acc = (acc > 0.f) ? acc : expm1f(acc);   // jax.nn.elu, alpha=1
        out[(size_t)node * COUT + lane] = acc;
    }
}

// ---------------------------------------------------------------- log_softmax rows
__global__ __launch_bounds__(256) void log_softmax_kernel(const float* __restrict__ in,
                                                          float* __restrict__ out,
                                                          int n, int C) {
    int lane = threadIdx.x & 63;
    int node = blockIdx.x * 4 + (threadIdx.x >> 6);
    if (node >= n) return;
    float v = (lane < C) ? in[(size_t)node * C + lane] : -__builtin_inff();
    float m = v;
    #pragma unroll
    for (int off = 32; off > 0; off >>= 1) m = fmaxf(m, __shfl_xor(m, off));
    float e = (lane < C) ? expf(v - m) : 0.f;
    float s = e;
    #pragma unroll
    for (int off = 32; off > 0; off >>= 1) s += __shfl_xor(s, off);
    if (lane < C) out[(size_t)node * C + lane] = (v - m) - logf(s);
}

// ---------------------------------------------------------------- launch

static inline size_t align_up(size_t x, size_t a) { return (x + a - 1) & ~(a - 1); }

extern "C" void kernel_launch(void* const* d_in, const int* in_sizes, int n_in,
                              void* d_out, int out_size, void* d_ws, size_t ws_size,
                              hipStream_t stream) {
    const float* x  = (const float*)d_in[0];
    const int*   ei = (const int*)d_in[1];     // [2][E] flat: src then dst
    const float* ea = (const float*)d_in[2];
    const float* W1 = (const float*)d_in[3];
    const float* b1 = (const float*)d_in[4];
    const float* W2 = (const float*)d_in[5];
    const float* b2 = (const float*)d_in[6];
    const float* W3 = (const float*)d_in[7];
    const float* b3 = (const float*)d_in[8];
    const float* W4 = (const float*)d_in[9];
    const float* b4 = (const float*)d_in[10];

    const int N = in_sizes[0] / 64;
    const int E = in_sizes[1] / 2;
    const int C = in_sizes[10];                // 40

    const int* src = ei;
    const int* dst = ei + E;

    // workspace carve-up
    char* p = (char*)d_ws;
    float* deg      = (float*)p; p += align_up((size_t)N * 4, 256);       // becomes dis
    float* selfnorm = (float*)p; p += align_up((size_t)N * 4, 256);
    int*   cnt      = (int*)p;   p += align_up((size_t)N * 4, 256);
    int*   offsets  = (int*)p;   p += align_up(((size_t)N + 1) * 4, 256);
    int2*  pairs    = (int2*)p;  p += align_up((size_t)E * 8, 256);
    float* tmp      = (float*)p; p += align_up((size_t)N * 64 * 4, 256);
    float* hbuf     = (float*)p; p += align_up((size_t)N * 64 * 4, 256);
    (void)ws_size;

    const int nb_n = (N + 255) / 256;
    const int nb_e = (E + 255) / 256 < 4096 ? (E + 255) / 256 : 4096;
    const int nb_w = (N + 3) / 4;              // 4 waves (nodes) per block

    // --- graph preprocessing (once per call) ---
    init_kernel<<<nb_n, 256, 0, stream>>>(deg, cnt, N);
    deg_accum_kernel<<<nb_e, 256, 0, stream>>>(dst, ea, deg, cnt, E);
    dis_kernel<<<nb_n, 256, 0, stream>>>(deg, selfnorm, N);
    scan_kernel<<<1, 1024, 0, stream>>>(cnt, offsets, N);
    scatter_kernel<<<nb_e, 256, 0, stream>>>(src, dst, ea, deg, offsets, cnt, pairs, E);

    // --- layer 1: x -> hbuf ---
    gemm_kernel<64><<<nb_n, 256, 0, stream>>>(x, W1, tmp, N);
    aggregate_kernel<64, true><<<nb_w, 256, 0, stream>>>(tmp, selfnorm, offsets, pairs, b1, hbuf, N);
    // --- layer 2 ---
    gemm_kernel<64><<<nb_n, 256, 0, stream>>>(hbuf, W2, tmp, N);
    aggregate_kernel<64, true><<<nb_w, 256, 0, stream>>>(tmp, selfnorm, offsets, pairs, b2, hbuf, N);
    // --- layer 3 ---
    gemm_kernel<64><<<nb_n, 256, 0, stream>>>(hbuf, W3, tmp, N);
    aggregate_kernel<64, true><<<nb_w, 256, 0, stream>>>(tmp, selfnorm, offsets, pairs, b3, hbuf, N);
    // --- layer 4 (no ELU) ---
    gemm_kernel<40><<<nb_n, 256, 0, stream>>>(hbuf, W4, tmp, N);
    aggregate_kernel<40, false><<<nb_w, 256, 0, stream>>>(tmp, selfnorm, offsets, pairs, b4, hbuf, N);

    // --- log_softmax -> d_out ---
    log_softmax_kernel<<<nb_w, 256, 0, stream>>>(hbuf, (float*)d_out, N, C);
}

// Round 5
// 514.026 us; speedup vs baseline: 1.3407x; 1.3407x over previous
//
#include <hip/hip_runtime.h>
#include <cstdint>
#include <cmath>

// GCN, 4 layers: h = elu(A_norm (h W) + b) x3, then log_softmax(A_norm (h W4) + b4)
// A_norm = D^-1/2 (A + I) D^-1/2, weighted; self-loops folded analytically.
//
// R4 changes vs R3 (deg_accum was 110us of atomic throughput):
//  - single packed u64 atomic per edge: cnt in bits[40:63], fixed-point(2^-24)
//    weight sum in bits[0:39]; atomic return value = edge rank in its CSR row
//    -> scatter needs NO atomics. 3.6M atomics -> 1.2M. Bitwise-deterministic deg.
//  - device-wide 3-kernel scan replaces single-block (1-CU) scan.
//  - 64-feature aggregation vectorized: wave = 4 edge-groups x 16 lanes x float4
//    (one dwordx4/lane, 1KiB/instr, 4 edges in flight), cross-group shfl reduce.

#define FIX_SCALE 16777216.0f   // 2^24

// ---------------------------------------------------------------- setup

__global__ __launch_bounds__(256) void init_kernel(unsigned long long* __restrict__ packed,
                                                   int n) {
    int i = blockIdx.x * 256 + threadIdx.x;
    if (i < n) packed[i] = 0ull;
}

// one 64-bit atomic per edge: count + fixed-point weighted degree; rank = old count
__global__ __launch_bounds__(256) void deg_hist_kernel(const int* __restrict__ dst,
                                                       const float* __restrict__ w,
                                                       unsigned long long* __restrict__ packed,
                                                       int* __restrict__ rank, int E) {
    int stride = gridDim.x * 256;
    for (int e = blockIdx.x * 256 + threadIdx.x; e < E; e += stride) {
        int d = dst[e];
        unsigned long long add =
            (1ull << 40) | (unsigned long long)(w[e] * FIX_SCALE + 0.5f);
        unsigned long long old = atomicAdd(&packed[d], add);
        rank[e] = (int)(old >> 40);
    }
}

// unpack: deg = 1 (self-loop) + fixed sum; dis = rsqrt(deg); cnt for scan
__global__ __launch_bounds__(256) void dis_kernel(const unsigned long long* __restrict__ packed,
                                                  float* __restrict__ dis,
                                                  float* __restrict__ selfnorm,
                                                  int* __restrict__ cnt, int n) {
    int i = blockIdx.x * 256 + threadIdx.x;
    if (i < n) {
        unsigned long long pk = packed[i];
        int c = (int)(pk >> 40);
        float wsum = (float)(pk & ((1ull << 40) - 1)) * (1.0f / FIX_SCALE);
        float d = 1.0f + wsum;                 // >= 1 always (self-loop), no zero case
        float r = rsqrtf(d);
        dis[i] = r;
        selfnorm[i] = r * r;
        cnt[i] = c;
    }
}

// ------------------------------------------------- device-wide scan (3 kernels)
// chunk = 1024 ints per block (256 thr x int4)

__global__ __launch_bounds__(256) void scan_block_kernel(const int* __restrict__ cnt,
                                                         int* __restrict__ offsets,
                                                         int* __restrict__ bsum, int n) {
    __shared__ int wtot[4];
    int t = threadIdx.x;
    int i = blockIdx.x * 1024 + t * 4;
    int4 v = make_int4(0, 0, 0, 0);
    if (i + 3 < n) v = *reinterpret_cast<const int4*>(cnt + i);
    else {
        if (i     < n) v.x = cnt[i];
        if (i + 1 < n) v.y = cnt[i + 1];
        if (i + 2 < n) v.z = cnt[i + 2];
        if (i + 3 < n) v.w = cnt[i + 3];
    }
    int tsum = v.x + v.y + v.z + v.w;
    int lane = t & 63, wid = t >> 6;
    int x = tsum;
    #pragma unroll
    for (int off = 1; off < 64; off <<= 1) {
        int tt = __shfl_up(x, off);
        if (lane >= off) x += tt;
    }
    if (lane == 63) wtot[wid] = x;
    __syncthreads();
    int wbase = 0;
    #pragma unroll
    for (int wv = 0; wv < 4; ++wv) if (wv < wid) wbase += wtot[wv];
    int e0 = wbase + x - tsum;                 // exclusive prefix, local to block
    int4 o;
    o.x = e0; o.y = e0 + v.x; o.z = o.y + v.y; o.w = o.z + v.z;
    if (i + 3 < n) *reinterpret_cast<int4*>(offsets + i) = o;
    else {
        if (i     < n) offsets[i]     = o.x;
        if (i + 1 < n) offsets[i + 1] = o.y;
        if (i + 2 < n) offsets[i + 2] = o.z;
        if (i + 3 < n) offsets[i + 3] = o.w;
    }
    if (t == 255) bsum[blockIdx.x] = wbase + x;   // block total
}

__global__ __launch_bounds__(64) void scan_bsum_kernel(int* __restrict__ bsum, int B) {
    int lane = threadIdx.x;
    int run = 0;
    for (int base = 0; base < B; base += 64) {
        int i = base + lane;
        int v = (i < B) ? bsum[i] : 0;
        int x = v;
        #pragma unroll
        for (int off = 1; off < 64; off <<= 1) {
            int t = __shfl_up(x, off);
            if (lane >= off) x += t;
        }
        if (i < B) bsum[i] = run + x - v;      // exclusive
        run += __shfl(x, 63);
    }
}

__global__ __launch_bounds__(256) void scan_add_kernel(int* __restrict__ offsets,
                                                       const int* __restrict__ bsum,
                                                       int n, int E) {
    int base = bsum[blockIdx.x];
    int i = blockIdx.x * 1024 + threadIdx.x * 4;
    if (i + 3 < n) {
        int4 o = *reinterpret_cast<int4*>(offsets + i);
        o.x += base; o.y += base; o.z += base; o.w += base;
        *reinterpret_cast<int4*>(offsets + i) = o;
    } else {
        for (int k = 0; k < 4; ++k) if (i + k < n) offsets[i + k] += base;
    }
    if (blockIdx.x == 0 && threadIdx.x == 0) offsets[n] = E;
}

// scatter, atomic-free: slot = offsets[dst] + rank; norm fused
__global__ __launch_bounds__(256) void scatter_kernel(const int* __restrict__ src,
                                                      const int* __restrict__ dst,
                                                      const float* __restrict__ w,
                                                      const int* __restrict__ rank,
                                                      const float* __restrict__ dis,
                                                      const int* __restrict__ offsets,
                                                      int2* __restrict__ pairs, int E) {
    int stride = gridDim.x * 256;
    for (int e = blockIdx.x * 256 + threadIdx.x; e < E; e += stride) {
        int s = src[e], d = dst[e];
        float nrm = dis[s] * w[e] * dis[d];
        pairs[offsets[d] + rank[e]] = make_int2(s, __float_as_int(nrm));
    }
}

// ---------------------------------------------------------------- GEMM: out = in @ W
template <int COUT>
__global__ __launch_bounds__(256) void gemm_kernel(const float* __restrict__ in,
                                                   const float* __restrict__ W,
                                                   float* __restrict__ out, int n) {
    __shared__ float WT[COUT][64];   // WT[c][k] = W[k][c]
    for (int idx = threadIdx.x; idx < 64 * COUT; idx += 256) {
        int k = idx / COUT, c = idx % COUT;
        WT[c][k] = W[idx];
    }
    __syncthreads();

    int row = blockIdx.x * 256 + threadIdx.x;
    if (row >= n) return;

    float4 h[16];
    const float4* inp = reinterpret_cast<const float4*>(in + (size_t)row * 64);
    #pragma unroll
    for (int i = 0; i < 16; ++i) h[i] = inp[i];

    float* outp = out + (size_t)row * COUT;
    #pragma unroll 2
    for (int c4 = 0; c4 < COUT / 4; ++c4) {
        float r[4];
        #pragma unroll
        for (int cc = 0; cc < 4; ++cc) {
            const float4* wt = reinterpret_cast<const float4*>(&WT[c4 * 4 + cc][0]);
            float4 a = make_float4(0.f, 0.f, 0.f, 0.f);
            #pragma unroll
            for (int i = 0; i < 16; ++i) {
                float4 w4 = wt[i];
                a.x = fmaf(h[i].x, w4.x, a.x);
                a.y = fmaf(h[i].y, w4.y, a.y);
                a.z = fmaf(h[i].z, w4.z, a.z);
                a.w = fmaf(h[i].w, w4.w, a.w);
            }
            r[cc] = (a.x + a.y) + (a.z + a.w);
        }
        *reinterpret_cast<float4*>(outp + c4 * 4) = make_float4(r[0], r[1], r[2], r[3]);
    }
}

// --------------------------------------- aggregation, 64 features, vectorized
// wave = 4 edge-groups (g) x 16 lanes (q); each lane loads float4 -> 1KiB/instr,
// 4 edges in flight per gather instruction. Cross-group reduce via shfl_xor.
template <bool ELU_ACT>
__global__ __launch_bounds__(256) void aggregate64_kernel(const float* __restrict__ tmp,
                                                          const float* __restrict__ selfnorm,
                                                          const int* __restrict__ offsets,
                                                          const int2* __restrict__ pairs,
                                                          const float* __restrict__ bias,
                                                          float* __restrict__ out, int n) {
    int lane = threadIdx.x & 63;
    int node = blockIdx.x * 4 + (threadIdx.x >> 6);
    if (node >= n) return;
    int g = lane >> 4;          // edge sub-group 0..3
    int q = lane & 15;          // float4 index within row

    float4 acc = make_float4(0.f, 0.f, 0.f, 0.f);
    int j = offsets[node];
    int end = offsets[node + 1];

    for (; j < end; j += 4) {
        int idx = j + g;
        bool valid = idx < end;
        int2 p = pairs[valid ? idx : j];
        float wv = valid ? __int_as_float(p.y) : 0.f;
        float4 row = *reinterpret_cast<const float4*>(tmp + (size_t)p.x * 64 + q * 4);
        acc.x = fmaf(wv, row.x, acc.x);
        acc.y = fmaf(wv, row.y, acc.y);
        acc.z = fmaf(wv, row.z, acc.z);
        acc.w = fmaf(wv, row.w, acc.w);
    }

    #pragma unroll
    for (int off = 16; off < 64; off <<= 1) {
        acc.x += __shfl_xor(acc.x, off);
        acc.y += __shfl_xor(acc.y, off);
        acc.z += __shfl_xor(acc.z, off);
        acc.w += __shfl_xor(acc.w, off);
    }

    if (g == 0) {
        float4 b4 = *reinterpret_cast<const float4*>(bias + q * 4);
        float4 t4 = *reinterpret_cast<const float4*>(tmp + (size_t)node * 64 + q * 4);
        float sn = selfnorm[node];
        float4 r;
        r.x = b4.x + fmaf(sn, t4.x, acc.x);
        r.y = b4.y + fmaf(sn, t4.y, acc.y);
        r.z = b4.z + fmaf(sn, t4.z, acc.z);
        r.w = b4.w + fmaf(sn, t4.w, acc.w);
        if (ELU_ACT) {
            r.x = (r.x > 0.f) ? r.x : expm1f(r.x);
            r.y = (r.y > 0.f) ? r.y : expm1f(r.y);
            r.z = (r.z > 0.f) ? r.z : expm1f(r.z);
            r.w = (r.w > 0.f) ? r.w : expm1f(r.w);
        }
        *reinterpret_cast<float4*>(out + (size_t)node * 64 + q * 4) = r;
    }
}

// ------------------------------------ aggregation, 40 features (layer 4), scalar
__global__ __launch_bounds__(256) void aggregate40_kernel(const float* __restrict__ tmp,
                                                          const float* __restrict__ selfnorm,
                                                          const int* __restrict__ offsets,
                                                          const int2* __restrict__ pairs,
                                                          const float* __restrict__ bias,
                                                          float* __restrict__ out, int n) {
    constexpr int COUT = 40;
    int lane = threadIdx.x & 63;
    int node = blockIdx.x * 4 + (threadIdx.x >> 6);
    if (node >= n) return;
    const bool act = lane < COUT;

    float acc = 0.f;
    if (act) acc = bias[lane] + selfnorm[node] * tmp[(size_t)node * COUT + lane];

    int j = offsets[node];
    int end = offsets[node + 1];
    for (; j + 4 <= end; j += 4) {
        int2 p[4];
        float v[4];
        #pragma unroll
        for (int u = 0; u < 4; ++u) p[u] = pairs[j + u];
        #pragma unroll
        for (int u = 0; u < 4; ++u)
            v[u] = act ? tmp[(size_t)p[u].x * COUT + lane] : 0.f;
        #pragma unroll
        for (int u = 0; u < 4; ++u)
            acc = fmaf(__int_as_float(p[u].y), v[u], acc);
    }
    for (; j < end; ++j) {
        int2 p = pairs[j];
        float v = act ? tmp[(size_t)p.x * COUT + lane] : 0.f;
        acc = fmaf(__int_as_float(p.y), v, acc);
    }
    if (act) out[(size_t)node * COUT + lane] = acc;
}

// ---------------------------------------------------------------- log_softmax rows
__global__ __launch_bounds__(256) void log_softmax_kernel(const float* __restrict__ in,
                                                          float* __restrict__ out,
                                                          int n, int C) {
    int lane = threadIdx.x & 63;
    int node = blockIdx.x * 4 + (threadIdx.x >> 6);
    if (node >= n) return;
    float v = (lane < C) ? in[(size_t)node * C + lane] : -__builtin_inff();
    float m = v;
    #pragma unroll
    for (int off = 32; off > 0; off >>= 1) m = fmaxf(m, __shfl_xor(m, off));
    float e = (lane < C) ? expf(v - m) : 0.f;
    float s = e;
    #pragma unroll
    for (int off = 32; off > 0; off >>= 1) s += __shfl_xor(s, off);
    if (lane < C) out[(size_t)node * C + lane] = (v - m) - logf(s);
}

// ---------------------------------------------------------------- launch

static inline size_t align_up(size_t x, size_t a) { return (x + a - 1) & ~(a - 1); }

extern "C" void kernel_launch(void* const* d_in, const int* in_sizes, int n_in,
                              void* d_out, int out_size, void* d_ws, size_t ws_size,
                              hipStream_t stream) {
    const float* x  = (const float*)d_in[0];
    const int*   ei = (const int*)d_in[1];     // [2][E] flat: src then dst (int32 via harness)
    const float* ea = (const float*)d_in[2];
    const float* W1 = (const float*)d_in[3];
    const float* b1 = (const float*)d_in[4];
    const float* W2 = (const float*)d_in[5];
    const float* b2 = (const float*)d_in[6];
    const float* W3 = (const float*)d_in[7];
    const float* b3 = (const float*)d_in[8];
    const float* W4 = (const float*)d_in[9];
    const float* b4 = (const float*)d_in[10];

    const int N = in_sizes[0] / 64;
    const int E = in_sizes[1] / 2;
    const int C = in_sizes[10];                // 40

    const int* src = ei;
    const int* dst = ei + E;

    const int B = (N + 1023) / 1024;           // scan chunks

    // workspace carve-up
    char* p = (char*)d_ws;
    unsigned long long* packed = (unsigned long long*)p; p += align_up((size_t)N * 8, 256);
    float* dis      = (float*)p; p += align_up((size_t)N * 4, 256);
    float* selfnorm = (float*)p; p += align_up((size_t)N * 4, 256);
    int*   cnt      = (int*)p;   p += align_up((size_t)N * 4, 256);
    int*   offsets  = (int*)p;   p += align_up(((size_t)N + 1) * 4, 256);
    int*   bsum     = (int*)p;   p += align_up(((size_t)B + 1) * 4, 256);
    int2*  pairs    = (int2*)p;  p += align_up(((size_t)E + 8) * 8, 256);
    float* tmp      = (float*)p; p += align_up((size_t)N * 64 * 4, 256);
    float* hbuf     = (float*)p; p += align_up((size_t)N * 64 * 4, 256);
    int*   rank     = (int*)tmp;                // aliases tmp: dead before gemm layer 1
    (void)ws_size;

    const int nb_n = (N + 255) / 256;
    int nb_e = (E + 255) / 256; if (nb_e > 4096) nb_e = 4096;
    const int nb_w = (N + 3) / 4;               // 4 nodes (waves) per block

    // --- graph preprocessing (deterministic, 1 atomic/edge) ---
    init_kernel<<<nb_n, 256, 0, stream>>>(packed, N);
    deg_hist_kernel<<<nb_e, 256, 0, stream>>>(dst, ea, packed, rank, E);
    dis_kernel<<<nb_n, 256, 0, stream>>>(packed, dis, selfnorm, cnt, N);
    scan_block_kernel<<<B, 256, 0, stream>>>(cnt, offsets, bsum, N);
    scan_bsum_kernel<<<1, 64, 0, stream>>>(bsum, B);
    scan_add_kernel<<<B, 256, 0, stream>>>(offsets, bsum, N, E);
    scatter_kernel<<<nb_e, 256, 0, stream>>>(src, dst, ea, rank, dis, offsets, pairs, E);

    // --- layer 1: x -> hbuf ---
    gemm_kernel<64><<<nb_n, 256, 0, stream>>>(x, W1, tmp, N);
    aggregate64_kernel<true><<<nb_w, 256, 0, stream>>>(tmp, selfnorm, offsets, pairs, b1, hbuf, N);
    // --- layer 2 ---
    gemm_kernel<64><<<nb_n, 256, 0, stream>>>(hbuf, W2, tmp, N);
    aggregate64_kernel<true><<<nb_w, 256, 0, stream>>>(tmp, selfnorm, offsets, pairs, b2, hbuf, N);
    // --- layer 3 ---
    gemm_kernel<64><<<nb_n, 256, 0, stream>>>(hbuf, W3, tmp, N);
    aggregate64_kernel<true><<<nb_w, 256, 0, stream>>>(tmp, selfnorm, offsets, pairs, b3, hbuf, N);
    // --- layer 4 (no ELU) ---
    gemm_kernel<40><<<nb_n, 256, 0, stream>>>(hbuf, W4, tmp, N);
    aggregate40_kernel<<<nb_w, 256, 0, stream>>>(tmp, selfnorm, offsets, pairs, b4, hbuf, N);

    // --- log_softmax -> d_out ---
    log_softmax_kernel<<<nb_w, 256, 0, stream>>>(hbuf, (float*)d_out, N, C);
}

// Round 6
// 440.779 us; speedup vs baseline: 1.5635x; 1.1662x over previous
//
#include <hip/hip_runtime.h>
#include <cstdint>
#include <cmath>

// GCN, 4 layers. R5 restructure: use linearity A(hW) = (Ah)W and fold the
// symmetric norm into the stored features:
//   g = dis (.) h   (scaled rows, produced by each GEMM epilogue)
//   A_norm h [d] = dis[d] * ( sum_e w_e * g[src_e]  +  g[d] )
// so: pairs = (src, raw w); scatter needs no dis; degree = exact CSR row-sum.
// Per layer: aggregate (16-lane group per node, float4 lanes, no shuffles)
// then GEMM (W in LDS) with bias+ELU+dis-scale fused; layer 4 GEMM fuses
// log_softmax and writes d_out directly.

// ---------------------------------------------------------------- setup

__global__ __launch_bounds__(256) void init_kernel(int* __restrict__ cnt, int n) {
    int i = blockIdx.x * 256 + threadIdx.x;
    if (i < n) cnt[i] = 0;
}

// count edges per destination; atomic return = rank of edge within its row
__global__ __launch_bounds__(256) void hist_kernel(const int* __restrict__ dst,
                                                   int* __restrict__ cnt,
                                                   int* __restrict__ rank, int E) {
    int stride = gridDim.x * 256;
    for (int e = blockIdx.x * 256 + threadIdx.x; e < E; e += stride) {
        rank[e] = atomicAdd(&cnt[dst[e]], 1);
    }
}

// ------------------------------------------------- device-wide scan (3 kernels)

__global__ __launch_bounds__(256) void scan_block_kernel(const int* __restrict__ cnt,
                                                         int* __restrict__ offsets,
                                                         int* __restrict__ bsum, int n) {
    __shared__ int wtot[4];
    int t = threadIdx.x;
    int i = blockIdx.x * 1024 + t * 4;
    int4 v = make_int4(0, 0, 0, 0);
    if (i + 3 < n) v = *reinterpret_cast<const int4*>(cnt + i);
    else {
        if (i     < n) v.x = cnt[i];
        if (i + 1 < n) v.y = cnt[i + 1];
        if (i + 2 < n) v.z = cnt[i + 2];
        if (i + 3 < n) v.w = cnt[i + 3];
    }
    int tsum = v.x + v.y + v.z + v.w;
    int lane = t & 63, wid = t >> 6;
    int x = tsum;
    #pragma unroll
    for (int off = 1; off < 64; off <<= 1) {
        int tt = __shfl_up(x, off);
        if (lane >= off) x += tt;
    }
    if (lane == 63) wtot[wid] = x;
    __syncthreads();
    int wbase = 0;
    #pragma unroll
    for (int wv = 0; wv < 4; ++wv) if (wv < wid) wbase += wtot[wv];
    int e0 = wbase + x - tsum;
    int4 o;
    o.x = e0; o.y = e0 + v.x; o.z = o.y + v.y; o.w = o.z + v.z;
    if (i + 3 < n) *reinterpret_cast<int4*>(offsets + i) = o;
    else {
        if (i     < n) offsets[i]     = o.x;
        if (i + 1 < n) offsets[i + 1] = o.y;
        if (i + 2 < n) offsets[i + 2] = o.z;
        if (i + 3 < n) offsets[i + 3] = o.w;
    }
    if (t == 255) bsum[blockIdx.x] = wbase + x;
}

__global__ __launch_bounds__(64) void scan_bsum_kernel(int* __restrict__ bsum, int B) {
    int lane = threadIdx.x;
    int run = 0;
    for (int base = 0; base < B; base += 64) {
        int i = base + lane;
        int v = (i < B) ? bsum[i] : 0;
        int x = v;
        #pragma unroll
        for (int off = 1; off < 64; off <<= 1) {
            int t = __shfl_up(x, off);
            if (lane >= off) x += t;
        }
        if (i < B) bsum[i] = run + x - v;
        run += __shfl(x, 63);
    }
}

__global__ __launch_bounds__(256) void scan_add_kernel(int* __restrict__ offsets,
                                                       const int* __restrict__ bsum,
                                                       int n, int E) {
    int base = bsum[blockIdx.x];
    int i = blockIdx.x * 1024 + threadIdx.x * 4;
    if (i + 3 < n) {
        int4 o = *reinterpret_cast<int4*>(offsets + i);
        o.x += base; o.y += base; o.z += base; o.w += base;
        *reinterpret_cast<int4*>(offsets + i) = o;
    } else {
        for (int k = 0; k < 4; ++k) if (i + k < n) offsets[i + k] += base;
    }
    if (blockIdx.x == 0 && threadIdx.x == 0) offsets[n] = E;
}

// scatter, atomic-free: pairs[offsets[dst]+rank] = (src, raw weight)
__global__ __launch_bounds__(256) void scatter_kernel(const int* __restrict__ src,
                                                      const int* __restrict__ dst,
                                                      const float* __restrict__ w,
                                                      const int* __restrict__ rank,
                                                      const int* __restrict__ offsets,
                                                      int2* __restrict__ pairs, int E) {
    int stride = gridDim.x * 256;
    for (int e = blockIdx.x * 256 + threadIdx.x; e < E; e += stride) {
        pairs[offsets[dst[e]] + rank[e]] = make_int2(src[e], __float_as_int(w[e]));
    }
}

// deg = 1 + row-sum of w; dis = rsqrt(deg). 16-lane group per node.
__global__ __launch_bounds__(256) void rowsum_dis_kernel(const int* __restrict__ offsets,
                                                         const int2* __restrict__ pairs,
                                                         float* __restrict__ dis, int n) {
    int node = blockIdx.x * 16 + (threadIdx.x >> 4);
    int q = threadIdx.x & 15;
    if (node >= n) return;
    int j0 = offsets[node], end = offsets[node + 1];
    float s = 0.f;
    for (int j = j0 + q; j < end; j += 16) s += __int_as_float(pairs[j].y);
    #pragma unroll
    for (int off = 8; off; off >>= 1) s += __shfl_xor(s, off);
    if (q == 0) dis[node] = rsqrtf(1.0f + s);
}

// g0 = dis (.) x  (one float4 per thread)
__global__ __launch_bounds__(256) void scale_kernel(const float* __restrict__ x,
                                                    const float* __restrict__ dis,
                                                    float* __restrict__ g, int n) {
    int i = blockIdx.x * 256 + threadIdx.x;          // float4 index
    if (i >= n * 16) return;
    float d = dis[i >> 4];
    float4 v = reinterpret_cast<const float4*>(x)[i];
    v.x *= d; v.y *= d; v.z *= d; v.w *= d;
    reinterpret_cast<float4*>(g)[i] = v;
}

// --------------------------------------- aggregation: agg[d] = dis[d]*(sum w*g[s] + g[d])
// 16-lane group per node (4 nodes/wave); lane q owns float4 #q of the 64-wide row.
// One edge gather = one wave VMEM instr moving 4 rows x 256B. No cross-lane reduce.
__global__ __launch_bounds__(256) void aggregate_kernel(const float* __restrict__ g,
                                                        const float* __restrict__ dis,
                                                        const int* __restrict__ offsets,
                                                        const int2* __restrict__ pairs,
                                                        float* __restrict__ aggout, int n) {
    int node = blockIdx.x * 16 + (threadIdx.x >> 4);
    int q = threadIdx.x & 15;
    if (node >= n) return;
    const float4* gt = reinterpret_cast<const float4*>(g);

    float4 acc = make_float4(0.f, 0.f, 0.f, 0.f);
    int j = offsets[node];
    int end = offsets[node + 1];

    for (; j + 4 <= end; j += 4) {
        int2 p0 = pairs[j], p1 = pairs[j + 1], p2 = pairs[j + 2], p3 = pairs[j + 3];
        float4 r0 = gt[(size_t)p0.x * 16 + q];
        float4 r1 = gt[(size_t)p1.x * 16 + q];
        float4 r2 = gt[(size_t)p2.x * 16 + q];
        float4 r3 = gt[(size_t)p3.x * 16 + q];
        float w0 = __int_as_float(p0.y), w1 = __int_as_float(p1.y);
        float w2 = __int_as_float(p2.y), w3 = __int_as_float(p3.y);
        acc.x = fmaf(w0, r0.x, acc.x); acc.y = fmaf(w0, r0.y, acc.y);
        acc.z = fmaf(w0, r0.z, acc.z); acc.w = fmaf(w0, r0.w, acc.w);
        acc.x = fmaf(w1, r1.x, acc.x); acc.y = fmaf(w1, r1.y, acc.y);
        acc.z = fmaf(w1, r1.z, acc.z); acc.w = fmaf(w1, r1.w, acc.w);
        acc.x = fmaf(w2, r2.x, acc.x); acc.y = fmaf(w2, r2.y, acc.y);
        acc.z = fmaf(w2, r2.z, acc.z); acc.w = fmaf(w2, r2.w, acc.w);
        acc.x = fmaf(w3, r3.x, acc.x); acc.y = fmaf(w3, r3.y, acc.y);
        acc.z = fmaf(w3, r3.z, acc.z); acc.w = fmaf(w3, r3.w, acc.w);
    }
    for (; j < end; ++j) {
        int2 p = pairs[j];
        float wv = __int_as_float(p.y);
        float4 r = gt[(size_t)p.x * 16 + q];
        acc.x = fmaf(wv, r.x, acc.x); acc.y = fmaf(wv, r.y, acc.y);
        acc.z = fmaf(wv, r.z, acc.z); acc.w = fmaf(wv, r.w, acc.w);
    }

    float4 self = gt[(size_t)node * 16 + q];
    float dn = dis[node];
    float4 r;
    r.x = dn * (acc.x + self.x);
    r.y = dn * (acc.y + self.y);
    r.z = dn * (acc.z + self.z);
    r.w = dn * (acc.w + self.w);
    reinterpret_cast<float4*>(aggout)[(size_t)node * 16 + q] = r;
}

// ------------------------------------------- GEMM 64x64 + bias + ELU + dis-scale
// out_row = dis[row] * elu(in_row @ W + b)   (produces next layer's g)
__global__ __launch_bounds__(256) void gemm64_kernel(const float* __restrict__ in,
                                                     const float* __restrict__ W,
                                                     const float* __restrict__ b,
                                                     const float* __restrict__ dis,
                                                     float* __restrict__ out, int n) {
    __shared__ float WT[64][64];   // WT[c][k] = W[k][c]
    for (int idx = threadIdx.x; idx < 64 * 64; idx += 256) {
        int k = idx >> 6, c = idx & 63;
        WT[c][k] = W[idx];
    }
    __syncthreads();

    int row = blockIdx.x * 256 + threadIdx.x;
    if (row >= n) return;

    float4 h[16];
    const float4* inp = reinterpret_cast<const float4*>(in + (size_t)row * 64);
    #pragma unroll
    for (int i = 0; i < 16; ++i) h[i] = inp[i];

    float dn = dis[row];
    float* outp = out + (size_t)row * 64;
    #pragma unroll 2
    for (int c4 = 0; c4 < 16; ++c4) {
        float4 bv = *reinterpret_cast<const float4*>(b + c4 * 4);
        float r[4];
        #pragma unroll
        for (int cc = 0; cc < 4; ++cc) {
            const float4* wt = reinterpret_cast<const float4*>(&WT[c4 * 4 + cc][0]);
            float4 a = make_float4(0.f, 0.f, 0.f, 0.f);
            #pragma unroll
            for (int i = 0; i < 16; ++i) {
                float4 w4 = wt[i];
                a.x = fmaf(h[i].x, w4.x, a.x);
                a.y = fmaf(h[i].y, w4.y, a.y);
                a.z = fmaf(h[i].z, w4.z, a.z);
                a.w = fmaf(h[i].w, w4.w, a.w);
            }
            float v = (a.x + a.y) + (a.z + a.w) + ((const float*)&bv)[cc];
            v = (v > 0.f) ? v : expm1f(v);      // ELU
            r[cc] = dn * v;                     // pre-scale for next aggregate
        }
        *reinterpret_cast<float4*>(outp + c4 * 4) = make_float4(r[0], r[1], r[2], r[3]);
    }
}

// ------------------------------- GEMM 64x40 + bias + fused row log_softmax -> d_out
__global__ __launch_bounds__(256) void gemm40_softmax_kernel(const float* __restrict__ in,
                                                             const float* __restrict__ W,
                                                             const float* __restrict__ b,
                                                             float* __restrict__ out, int n) {
    __shared__ float WT[40][64];   // WT[c][k] = W[k][c]
    for (int idx = threadIdx.x; idx < 64 * 40; idx += 256) {
        int k = idx / 40, c = idx % 40;
        WT[c][k] = W[idx];
    }
    __syncthreads();

    int row = blockIdx.x * 256 + threadIdx.x;
    if (row >= n) return;

    float4 h[16];
    const float4* inp = reinterpret_cast<const float4*>(in + (size_t)row * 64);
    #pragma unroll
    for (int i = 0; i < 16; ++i) h[i] = inp[i];

    float r[40];
    #pragma unroll 2
    for (int c = 0; c < 40; ++c) {
        const float4* wt = reinterpret_cast<const float4*>(&WT[c][0]);
        float4 a = make_float4(0.f, 0.f, 0.f, 0.f);
        #pragma unroll
        for (int i = 0; i < 16; ++i) {
            float4 w4 = wt[i];
            a.x = fmaf(h[i].x, w4.x, a.x);
            a.y = fmaf(h[i].y, w4.y, a.y);
            a.z = fmaf(h[i].z, w4.z, a.z);
            a.w = fmaf(h[i].w, w4.w, a.w);
        }
        r[c] = (a.x + a.y) + (a.z + a.w) + b[c];
    }

    float m = r[0];
    #pragma unroll
    for (int c = 1; c < 40; ++c) m = fmaxf(m, r[c]);
    float s = 0.f;
    #pragma unroll
    for (int c = 0; c < 40; ++c) s += expf(r[c] - m);
    float ls = logf(s) + m;

    float* outp = out + (size_t)row * 40;
    #pragma unroll
    for (int c4 = 0; c4 < 10; ++c4) {
        *reinterpret_cast<float4*>(outp + c4 * 4) =
            make_float4(r[c4 * 4] - ls, r[c4 * 4 + 1] - ls,
                        r[c4 * 4 + 2] - ls, r[c4 * 4 + 3] - ls);
    }
}

// ---------------------------------------------------------------- launch

static inline size_t align_up(size_t x, size_t a) { return (x + a - 1) & ~(a - 1); }

extern "C" void kernel_launch(void* const* d_in, const int* in_sizes, int n_in,
                              void* d_out, int out_size, void* d_ws, size_t ws_size,
                              hipStream_t stream) {
    const float* x  = (const float*)d_in[0];
    const int*   ei = (const int*)d_in[1];     // [2][E] flat: src then dst
    const float* ea = (const float*)d_in[2];
    const float* W1 = (const float*)d_in[3];
    const float* b1 = (const float*)d_in[4];
    const float* W2 = (const float*)d_in[5];
    const float* b2 = (const float*)d_in[6];
    const float* W3 = (const float*)d_in[7];
    const float* b3 = (const float*)d_in[8];
    const float* W4 = (const float*)d_in[9];
    const float* b4 = (const float*)d_in[10];

    const int N = in_sizes[0] / 64;
    const int E = in_sizes[1] / 2;

    const int* src = ei;
    const int* dst = ei + E;

    const int B = (N + 1023) / 1024;

    // workspace carve-up
    char* p = (char*)d_ws;
    int*   cnt     = (int*)p;   p += align_up((size_t)N * 4, 256);
    int*   offsets = (int*)p;   p += align_up(((size_t)N + 1) * 4, 256);
    int*   bsum    = (int*)p;   p += align_up(((size_t)B + 1) * 4, 256);
    float* dis     = (float*)p; p += align_up((size_t)N * 4, 256);
    int2*  pairs   = (int2*)p;  p += align_up(((size_t)E + 8) * 8, 256);
    float* gA      = (float*)p; p += align_up((size_t)N * 64 * 4, 256);
    float* gB      = (float*)p; p += align_up((size_t)N * 64 * 4, 256);
    int*   rank    = (int*)gA;  // aliases gA: dead before scale_kernel writes gA
    (void)ws_size;

    const int nb_n  = (N + 255) / 256;
    int nb_e = (E + 255) / 256; if (nb_e > 4096) nb_e = 4096;
    const int nb_g  = (N + 15) / 16;            // 16-lane-group kernels
    const int nb_s  = ((size_t)N * 16 + 255) / 256;

    // --- graph preprocessing ---
    init_kernel<<<nb_n, 256, 0, stream>>>(cnt, N);
    hist_kernel<<<nb_e, 256, 0, stream>>>(dst, cnt, rank, E);
    scan_block_kernel<<<B, 256, 0, stream>>>(cnt, offsets, bsum, N);
    scan_bsum_kernel<<<1, 64, 0, stream>>>(bsum, B);
    scan_add_kernel<<<B, 256, 0, stream>>>(offsets, bsum, N, E);
    scatter_kernel<<<nb_e, 256, 0, stream>>>(src, dst, ea, rank, offsets, pairs, E);
    rowsum_dis_kernel<<<nb_g, 256, 0, stream>>>(offsets, pairs, dis, N);

    // --- g0 = dis (.) x ---
    scale_kernel<<<nb_s, 256, 0, stream>>>(x, dis, gA, N);

    // --- layer 1 ---
    aggregate_kernel<<<nb_g, 256, 0, stream>>>(gA, dis, offsets, pairs, gB, N);
    gemm64_kernel<<<nb_n, 256, 0, stream>>>(gB, W1, b1, dis, gA, N);
    // --- layer 2 ---
    aggregate_kernel<<<nb_g, 256, 0, stream>>>(gA, dis, offsets, pairs, gB, N);
    gemm64_kernel<<<nb_n, 256, 0, stream>>>(gB, W2, b2, dis, gA, N);
    // --- layer 3 ---
    aggregate_kernel<<<nb_g, 256, 0, stream>>>(gA, dis, offsets, pairs, gB, N);
    gemm64_kernel<<<nb_n, 256, 0, stream>>>(gB, W3, b3, dis, gA, N);
    // --- layer 4: aggregate then GEMM40 + log_softmax -> d_out ---
    aggregate_kernel<<<nb_g, 256, 0, stream>>>(gA, dis, offsets, pairs, gB, N);
    gemm40_softmax_kernel<<<nb_n, 256, 0, stream>>>(gB, W4, b4, (float*)d_out, N);
}

// Round 7
// 365.049 us; speedup vs baseline: 1.8879x; 1.2075x over previous
//
#include <hip/hip_runtime.h>
#include <hip/hip_fp16.h>
#include <cstdint>
#include <cmath>

// GCN, 4 layers. Structure (R5): A(hW) = (Ah)W with norm folded into features:
//   g = dis (.) h  stored FP16 (R6: halves the dominant gather traffic),
//   A_norm h [d] = dis[d] * ( sum_e w_e * g[src_e] + g[d] )
// CSR built once per call (atomic hist w/ rank capture -> scan -> atomic-free
// scatter). Per layer: aggregate (8-lane group per node, half8 lanes, fp32
// accum) then GEMM (W^T in LDS) with bias+ELU+dis-scale+fp16-convert fused;
// layer 4 GEMM fuses log_softmax and writes d_out.

// ---------------------------------------------------------------- setup

__global__ __launch_bounds__(256) void init_kernel(int* __restrict__ cnt, int n) {
    int i = blockIdx.x * 256 + threadIdx.x;
    if (i < n) cnt[i] = 0;
}

// count edges per destination; atomic return = rank of edge within its row
__global__ __launch_bounds__(256) void hist_kernel(const int* __restrict__ dst,
                                                   int* __restrict__ cnt,
                                                   int* __restrict__ rank, int E) {
    int stride = gridDim.x * 256;
    for (int e = blockIdx.x * 256 + threadIdx.x; e < E; e += stride) {
        rank[e] = atomicAdd(&cnt[dst[e]], 1);
    }
}

// ------------------------------------------------- device-wide scan (3 kernels)

__global__ __launch_bounds__(256) void scan_block_kernel(const int* __restrict__ cnt,
                                                         int* __restrict__ offsets,
                                                         int* __restrict__ bsum, int n) {
    __shared__ int wtot[4];
    int t = threadIdx.x;
    int i = blockIdx.x * 1024 + t * 4;
    int4 v = make_int4(0, 0, 0, 0);
    if (i + 3 < n) v = *reinterpret_cast<const int4*>(cnt + i);
    else {
        if (i     < n) v.x = cnt[i];
        if (i + 1 < n) v.y = cnt[i + 1];
        if (i + 2 < n) v.z = cnt[i + 2];
        if (i + 3 < n) v.w = cnt[i + 3];
    }
    int tsum = v.x + v.y + v.z + v.w;
    int lane = t & 63, wid = t >> 6;
    int x = tsum;
    #pragma unroll
    for (int off = 1; off < 64; off <<= 1) {
        int tt = __shfl_up(x, off);
        if (lane >= off) x += tt;
    }
    if (lane == 63) wtot[wid] = x;
    __syncthreads();
    int wbase = 0;
    #pragma unroll
    for (int wv = 0; wv < 4; ++wv) if (wv < wid) wbase += wtot[wv];
    int e0 = wbase + x - tsum;
    int4 o;
    o.x = e0; o.y = e0 + v.x; o.z = o.y + v.y; o.w = o.z + v.z;
    if (i + 3 < n) *reinterpret_cast<int4*>(offsets + i) = o;
    else {
        if (i     < n) offsets[i]     = o.x;
        if (i + 1 < n) offsets[i + 1] = o.y;
        if (i + 2 < n) offsets[i + 2] = o.z;
        if (i + 3 < n) offsets[i + 3] = o.w;
    }
    if (t == 255) bsum[blockIdx.x] = wbase + x;
}

__global__ __launch_bounds__(64) void scan_bsum_kernel(int* __restrict__ bsum, int B) {
    int lane = threadIdx.x;
    int run = 0;
    for (int base = 0; base < B; base += 64) {
        int i = base + lane;
        int v = (i < B) ? bsum[i] : 0;
        int x = v;
        #pragma unroll
        for (int off = 1; off < 64; off <<= 1) {
            int t = __shfl_up(x, off);
            if (lane >= off) x += t;
        }
        if (i < B) bsum[i] = run + x - v;
        run += __shfl(x, 63);
    }
}

__global__ __launch_bounds__(256) void scan_add_kernel(int* __restrict__ offsets,
                                                       const int* __restrict__ bsum,
                                                       int n, int E) {
    int base = bsum[blockIdx.x];
    int i = blockIdx.x * 1024 + threadIdx.x * 4;
    if (i + 3 < n) {
        int4 o = *reinterpret_cast<int4*>(offsets + i);
        o.x += base; o.y += base; o.z += base; o.w += base;
        *reinterpret_cast<int4*>(offsets + i) = o;
    } else {
        for (int k = 0; k < 4; ++k) if (i + k < n) offsets[i + k] += base;
    }
    if (blockIdx.x == 0 && threadIdx.x == 0) offsets[n] = E;
}

// scatter, atomic-free: pairs[offsets[dst]+rank] = (src, raw weight)
__global__ __launch_bounds__(256) void scatter_kernel(const int* __restrict__ src,
                                                      const int* __restrict__ dst,
                                                      const float* __restrict__ w,
                                                      const int* __restrict__ rank,
                                                      const int* __restrict__ offsets,
                                                      int2* __restrict__ pairs, int E) {
    int stride = gridDim.x * 256;
    for (int e = blockIdx.x * 256 + threadIdx.x; e < E; e += stride) {
        pairs[offsets[dst[e]] + rank[e]] = make_int2(src[e], __float_as_int(w[e]));
    }
}

// deg = 1 + row-sum of w; dis = rsqrt(deg). 16-lane group per node.
__global__ __launch_bounds__(256) void rowsum_dis_kernel(const int* __restrict__ offsets,
                                                         const int2* __restrict__ pairs,
                                                         float* __restrict__ dis, int n) {
    int node = blockIdx.x * 16 + (threadIdx.x >> 4);
    int q = threadIdx.x & 15;
    if (node >= n) return;
    int j0 = offsets[node], end = offsets[node + 1];
    float s = 0.f;
    for (int j = j0 + q; j < end; j += 16) s += __int_as_float(pairs[j].y);
    #pragma unroll
    for (int off = 8; off; off >>= 1) s += __shfl_xor(s, off);
    if (q == 0) dis[node] = rsqrtf(1.0f + s);
}

// g0 = fp16( dis (.) x ); one thread per 8 features
__global__ __launch_bounds__(256) void scale_kernel(const float* __restrict__ x,
                                                    const float* __restrict__ dis,
                                                    __half* __restrict__ g, int n) {
    int i = blockIdx.x * 256 + threadIdx.x;          // 8-float unit index
    if (i >= n * 8) return;
    float d = dis[i >> 3];
    float4 a = reinterpret_cast<const float4*>(x)[i * 2];
    float4 b = reinterpret_cast<const float4*>(x)[i * 2 + 1];
    __half2 h[4];
    h[0] = __float22half2_rn(make_float2(d * a.x, d * a.y));
    h[1] = __float22half2_rn(make_float2(d * a.z, d * a.w));
    h[2] = __float22half2_rn(make_float2(d * b.x, d * b.y));
    h[3] = __float22half2_rn(make_float2(d * b.z, d * b.w));
    reinterpret_cast<float4*>(g)[i] = *reinterpret_cast<float4*>(h);
}

// --------------------------------------- aggregation: agg[d] = dis[d]*(sum w*g[s] + g[d])
// 8-lane group per node (8 nodes/wave); lane q owns half8 #q (features 8q..8q+8).
// One edge gather = one wave VMEM instr moving 8 rows x 128B. fp32 accumulate.
__device__ __forceinline__ void accum8(float* acc, float4 rv, float w) {
    const __half2* h = reinterpret_cast<const __half2*>(&rv);
    #pragma unroll
    for (int k = 0; k < 4; ++k) {
        float2 f = __half22float2(h[k]);
        acc[2 * k]     = fmaf(w, f.x, acc[2 * k]);
        acc[2 * k + 1] = fmaf(w, f.y, acc[2 * k + 1]);
    }
}

__global__ __launch_bounds__(256) void aggregate_kernel(const __half* __restrict__ g,
                                                        const float* __restrict__ dis,
                                                        const int* __restrict__ offsets,
                                                        const int2* __restrict__ pairs,
                                                        float* __restrict__ aggout, int n) {
    int node = blockIdx.x * 32 + (threadIdx.x >> 3);
    int q = threadIdx.x & 7;
    if (node >= n) return;
    const float4* gt = reinterpret_cast<const float4*>(g);   // row = 8 x float4 (128B)

    float acc[8] = {0.f, 0.f, 0.f, 0.f, 0.f, 0.f, 0.f, 0.f};
    int j = offsets[node];
    int end = offsets[node + 1];

    for (; j + 4 <= end; j += 4) {
        int2 p0 = pairs[j], p1 = pairs[j + 1], p2 = pairs[j + 2], p3 = pairs[j + 3];
        float4 r0 = gt[(size_t)p0.x * 8 + q];
        float4 r1 = gt[(size_t)p1.x * 8 + q];
        float4 r2 = gt[(size_t)p2.x * 8 + q];
        float4 r3 = gt[(size_t)p3.x * 8 + q];
        accum8(acc, r0, __int_as_float(p0.y));
        accum8(acc, r1, __int_as_float(p1.y));
        accum8(acc, r2, __int_as_float(p2.y));
        accum8(acc, r3, __int_as_float(p3.y));
    }
    for (; j < end; ++j) {
        int2 p = pairs[j];
        float4 r = gt[(size_t)p.x * 8 + q];
        accum8(acc, r, __int_as_float(p.y));
    }

    // self term (weight 1)
    float4 rs = gt[(size_t)node * 8 + q];
    accum8(acc, rs, 1.0f);

    float dn = dis[node];
    float4 o0 = make_float4(dn * acc[0], dn * acc[1], dn * acc[2], dn * acc[3]);
    float4 o1 = make_float4(dn * acc[4], dn * acc[5], dn * acc[6], dn * acc[7]);
    float4* outp = reinterpret_cast<float4*>(aggout) + (size_t)node * 16 + q * 2;
    outp[0] = o0;
    outp[1] = o1;
}

// ------------------------------------------- GEMM 64x64 + bias + ELU + dis-scale -> fp16
// g_next_row = fp16( dis[row] * elu(in_row @ W + b) )
__global__ __launch_bounds__(256) void gemm64_kernel(const float* __restrict__ in,
                                                     const float* __restrict__ W,
                                                     const float* __restrict__ b,
                                                     const float* __restrict__ dis,
                                                     __half* __restrict__ out, int n) {
    __shared__ float WT[64][64];   // WT[c][k] = W[k][c]
    for (int idx = threadIdx.x; idx < 64 * 64; idx += 256) {
        int k = idx >> 6, c = idx & 63;
        WT[c][k] = W[idx];
    }
    __syncthreads();

    int row = blockIdx.x * 256 + threadIdx.x;
    if (row >= n) return;

    float4 h[16];
    const float4* inp = reinterpret_cast<const float4*>(in + (size_t)row * 64);
    #pragma unroll
    for (int i = 0; i < 16; ++i) h[i] = inp[i];

    float dn = dis[row];
    __half* outp = out + (size_t)row * 64;
    #pragma unroll 2
    for (int c4 = 0; c4 < 16; ++c4) {
        float4 bv = *reinterpret_cast<const float4*>(b + c4 * 4);
        float r[4];
        #pragma unroll
        for (int cc = 0; cc < 4; ++cc) {
            const float4* wt = reinterpret_cast<const float4*>(&WT[c4 * 4 + cc][0]);
            float4 a = make_float4(0.f, 0.f, 0.f, 0.f);
            #pragma unroll
            for (int i = 0; i < 16; ++i) {
                float4 w4 = wt[i];
                a.x = fmaf(h[i].x, w4.x, a.x);
                a.y = fmaf(h[i].y, w4.y, a.y);
                a.z = fmaf(h[i].z, w4.z, a.z);
                a.w = fmaf(h[i].w, w4.w, a.w);
            }
            float v = (a.x + a.y) + (a.z + a.w) + ((const float*)&bv)[cc];
            v = (v > 0.f) ? v : expm1f(v);      // ELU
            r[cc] = dn * v;                     // pre-scale for next aggregate
        }
        __half2 lo = __float22half2_rn(make_float2(r[0], r[1]));
        __half2 hi = __float22half2_rn(make_float2(r[2], r[3]));
        __half2 pk[2] = {lo, hi};
        *reinterpret_cast<float2*>(outp + c4 * 4) = *reinterpret_cast<float2*>(pk);
    }
}

// ------------------------------- GEMM 64x40 + bias + fused row log_softmax -> d_out
__global__ __launch_bounds__(256) void gemm40_softmax_kernel(const float* __restrict__ in,
                                                             const float* __restrict__ W,
                                                             const float* __restrict__ b,
                                                             float* __restrict__ out, int n) {
    __shared__ float WT[40][64];   // WT[c][k] = W[k][c]
    for (int idx = threadIdx.x; idx < 64 * 40; idx += 256) {
        int k = idx / 40, c = idx % 40;
        WT[c][k] = W[idx];
    }
    __syncthreads();

    int row = blockIdx.x * 256 + threadIdx.x;
    if (row >= n) return;

    float4 h[16];
    const float4* inp = reinterpret_cast<const float4*>(in + (size_t)row * 64);
    #pragma unroll
    for (int i = 0; i < 16; ++i) h[i] = inp[i];

    float r[40];
    #pragma unroll 2
    for (int c = 0; c < 40; ++c) {
        const float4* wt = reinterpret_cast<const float4*>(&WT[c][0]);
        float4 a = make_float4(0.f, 0.f, 0.f, 0.f);
        #pragma unroll
        for (int i = 0; i < 16; ++i) {
            float4 w4 = wt[i];
            a.x = fmaf(h[i].x, w4.x, a.x);
            a.y = fmaf(h[i].y, w4.y, a.y);
            a.z = fmaf(h[i].z, w4.z, a.z);
            a.w = fmaf(h[i].w, w4.w, a.w);
        }
        r[c] = (a.x + a.y) + (a.z + a.w) + b[c];
    }

    float m = r[0];
    #pragma unroll
    for (int c = 1; c < 40; ++c) m = fmaxf(m, r[c]);
    float s = 0.f;
    #pragma unroll
    for (int c = 0; c < 40; ++c) s += expf(r[c] - m);
    float ls = logf(s) + m;

    float* outp = out + (size_t)row * 40;
    #pragma unroll
    for (int c4 = 0; c4 < 10; ++c4) {
        *reinterpret_cast<float4*>(outp + c4 * 4) =
            make_float4(r[c4 * 4] - ls, r[c4 * 4 + 1] - ls,
                        r[c4 * 4 + 2] - ls, r[c4 * 4 + 3] - ls);
    }
}

// ---------------------------------------------------------------- launch

static inline size_t align_up(size_t x, size_t a) { return (x + a - 1) & ~(a - 1); }

extern "C" void kernel_launch(void* const* d_in, const int* in_sizes, int n_in,
                              void* d_out, int out_size, void* d_ws, size_t ws_size,
                              hipStream_t stream) {
    const float* x  = (const float*)d_in[0];
    const int*   ei = (const int*)d_in[1];     // [2][E] flat: src then dst
    const float* ea = (const float*)d_in[2];
    const float* W1 = (const float*)d_in[3];
    const float* b1 = (const float*)d_in[4];
    const float* W2 = (const float*)d_in[5];
    const float* b2 = (const float*)d_in[6];
    const float* W3 = (const float*)d_in[7];
    const float* b3 = (const float*)d_in[8];
    const float* W4 = (const float*)d_in[9];
    const float* b4 = (const float*)d_in[10];

    const int N = in_sizes[0] / 64;
    const int E = in_sizes[1] / 2;

    const int* src = ei;
    const int* dst = ei + E;

    const int B = (N + 1023) / 1024;

    // workspace carve-up
    char* p = (char*)d_ws;
    int*    cnt     = (int*)p;    p += align_up((size_t)N * 4, 256);
    int*    offsets = (int*)p;    p += align_up(((size_t)N + 1) * 4, 256);
    int*    bsum    = (int*)p;    p += align_up(((size_t)B + 1) * 4, 256);
    float*  dis     = (float*)p;  p += align_up((size_t)N * 4, 256);
    int2*   pairs   = (int2*)p;   p += align_up(((size_t)E + 8) * 8, 256);
    __half* gA      = (__half*)p; p += align_up((size_t)N * 64 * 2, 256);  // fp16 features
    float*  fA      = (float*)p;  p += align_up((size_t)N * 64 * 4, 256);  // fp32 aggregate
    int*    rank    = (int*)gA;   // aliases gA: dead before scale_kernel writes gA
    (void)ws_size;

    const int nb_n  = (N + 255) / 256;
    int nb_e = (E + 255) / 256; if (nb_e > 4096) nb_e = 4096;
    const int nb_g16 = (N + 15) / 16;           // 16-lane-group kernels
    const int nb_g8  = (N + 31) / 32;           // 8-lane-group aggregate
    const int nb_s   = ((size_t)N * 8 + 255) / 256;

    // --- graph preprocessing ---
    init_kernel<<<nb_n, 256, 0, stream>>>(cnt, N);
    hist_kernel<<<nb_e, 256, 0, stream>>>(dst, cnt, rank, E);
    scan_block_kernel<<<B, 256, 0, stream>>>(cnt, offsets, bsum, N);
    scan_bsum_kernel<<<1, 64, 0, stream>>>(bsum, B);
    scan_add_kernel<<<B, 256, 0, stream>>>(offsets, bsum, N, E);
    scatter_kernel<<<nb_e, 256, 0, stream>>>(src, dst, ea, rank, offsets, pairs, E);
    rowsum_dis_kernel<<<nb_g16, 256, 0, stream>>>(offsets, pairs, dis, N);

    // --- g0 = fp16(dis (.) x) ---
    scale_kernel<<<nb_s, 256, 0, stream>>>(x, dis, gA, N);

    // --- layer 1 ---
    aggregate_kernel<<<nb_g8, 256, 0, stream>>>(gA, dis, offsets, pairs, fA, N);
    gemm64_kernel<<<nb_n, 256, 0, stream>>>(fA, W1, b1, dis, gA, N);
    // --- layer 2 ---
    aggregate_kernel<<<nb_g8, 256, 0, stream>>>(gA, dis, offsets, pairs, fA, N);
    gemm64_kernel<<<nb_n, 256, 0, stream>>>(fA, W2, b2, dis, gA, N);
    // --- layer 3 ---
    aggregate_kernel<<<nb_g8, 256, 0, stream>>>(gA, dis, offsets, pairs, fA, N);
    gemm64_kernel<<<nb_n, 256, 0, stream>>>(fA, W3, b3, dis, gA, N);
    // --- layer 4: aggregate then GEMM40 + log_softmax -> d_out ---
    aggregate_kernel<<<nb_g8, 256, 0, stream>>>(gA, dis, offsets, pairs, fA, N);
    gemm40_softmax_kernel<<<nb_n, 256, 0, stream>>>(fA, W4, b4, (float*)d_out, N);
}

// Round 8
// 353.342 us; speedup vs baseline: 1.9504x; 1.0331x over previous
//
#include <hip/hip_runtime.h>
#include <hip/hip_fp16.h>
#include <cstdint>
#include <cmath>

// GCN, 4 layers. Structure: A(hW) = (Ah)W with norm folded into features:
//   g = dis (.) h  stored FP16 (halves the dominant gather traffic),
//   A_norm h [d] = dis[d] * ( sum_e w_e * g[src_e] + g[d] )
// CSR built once per call (atomic hist w/ rank capture -> scan -> atomic-free
// scatter). R7 additions: hist/scatter ILP-8/4 (returning-atomic latency was
// the #1 cost: 8 independent atomics in flight per thread before first wait);
// aggregate writes fp16 too (GEMMs convert on load).

// ---------------------------------------------------------------- setup

__global__ __launch_bounds__(256) void init_kernel(int* __restrict__ cnt, int n) {
    int i = blockIdx.x * 256 + threadIdx.x;
    if (i < n) cnt[i] = 0;
}

// count edges per destination; atomic return = rank of edge within its row.
// ILP-8: issue 8 independent returning atomics before any dependent use, so
// the ~900cy atomic round-trip is paid once per 8, not once per 1.
__global__ __launch_bounds__(256) void hist_kernel(const int* __restrict__ dst,
                                                   int* __restrict__ cnt,
                                                   int* __restrict__ rank, int E) {
    int t = blockIdx.x * 2048 + threadIdx.x;
    if (t + 1792 < E) {
        int d[8];
        #pragma unroll
        for (int u = 0; u < 8; ++u) d[u] = dst[t + u * 256];
        int r[8];
        #pragma unroll
        for (int u = 0; u < 8; ++u) r[u] = atomicAdd(&cnt[d[u]], 1);
        #pragma unroll
        for (int u = 0; u < 8; ++u) rank[t + u * 256] = r[u];
    } else {
        #pragma unroll
        for (int u = 0; u < 8; ++u) {
            int e = t + u * 256;
            if (e < E) rank[e] = atomicAdd(&cnt[dst[e]], 1);
        }
    }
}

// ------------------------------------------------- device-wide scan (3 kernels)

__global__ __launch_bounds__(256) void scan_block_kernel(const int* __restrict__ cnt,
                                                         int* __restrict__ offsets,
                                                         int* __restrict__ bsum, int n) {
    __shared__ int wtot[4];
    int t = threadIdx.x;
    int i = blockIdx.x * 1024 + t * 4;
    int4 v = make_int4(0, 0, 0, 0);
    if (i + 3 < n) v = *reinterpret_cast<const int4*>(cnt + i);
    else {
        if (i     < n) v.x = cnt[i];
        if (i + 1 < n) v.y = cnt[i + 1];
        if (i + 2 < n) v.z = cnt[i + 2];
        if (i + 3 < n) v.w = cnt[i + 3];
    }
    int tsum = v.x + v.y + v.z + v.w;
    int lane = t & 63, wid = t >> 6;
    int x = tsum;
    #pragma unroll
    for (int off = 1; off < 64; off <<= 1) {
        int tt = __shfl_up(x, off);
        if (lane >= off) x += tt;
    }
    if (lane == 63) wtot[wid] = x;
    __syncthreads();
    int wbase = 0;
    #pragma unroll
    for (int wv = 0; wv < 4; ++wv) if (wv < wid) wbase += wtot[wv];
    int e0 = wbase + x - tsum;
    int4 o;
    o.x = e0; o.y = e0 + v.x; o.z = o.y + v.y; o.w = o.z + v.z;
    if (i + 3 < n) *reinterpret_cast<int4*>(offsets + i) = o;
    else {
        if (i     < n) offsets[i]     = o.x;
        if (i + 1 < n) offsets[i + 1] = o.y;
        if (i + 2 < n) offsets[i + 2] = o.z;
        if (i + 3 < n) offsets[i + 3] = o.w;
    }
    if (t == 255) bsum[blockIdx.x] = wbase + x;
}

__global__ __launch_bounds__(64) void scan_bsum_kernel(int* __restrict__ bsum, int B) {
    int lane = threadIdx.x;
    int run = 0;
    for (int base = 0; base < B; base += 64) {
        int i = base + lane;
        int v = (i < B) ? bsum[i] : 0;
        int x = v;
        #pragma unroll
        for (int off = 1; off < 64; off <<= 1) {
            int t = __shfl_up(x, off);
            if (lane >= off) x += t;
        }
        if (i < B) bsum[i] = run + x - v;
        run += __shfl(x, 63);
    }
}

__global__ __launch_bounds__(256) void scan_add_kernel(int* __restrict__ offsets,
                                                       const int* __restrict__ bsum,
                                                       int n, int E) {
    int base = bsum[blockIdx.x];
    int i = blockIdx.x * 1024 + threadIdx.x * 4;
    if (i + 3 < n) {
        int4 o = *reinterpret_cast<int4*>(offsets + i);
        o.x += base; o.y += base; o.z += base; o.w += base;
        *reinterpret_cast<int4*>(offsets + i) = o;
    } else {
        for (int k = 0; k < 4; ++k) if (i + k < n) offsets[i + k] += base;
    }
    if (blockIdx.x == 0 && threadIdx.x == 0) offsets[n] = E;
}

// scatter, atomic-free: pairs[offsets[dst]+rank] = (src, raw weight). ILP-4.
__global__ __launch_bounds__(256) void scatter_kernel(const int* __restrict__ src,
                                                      const int* __restrict__ dst,
                                                      const float* __restrict__ w,
                                                      const int* __restrict__ rank,
                                                      const int* __restrict__ offsets,
                                                      int2* __restrict__ pairs, int E) {
    int t = blockIdx.x * 1024 + threadIdx.x;
    if (t + 768 < E) {
        int d[4], s[4], r[4]; float wv[4];
        #pragma unroll
        for (int u = 0; u < 4; ++u) {
            int e = t + u * 256;
            d[u] = dst[e]; s[u] = src[e]; wv[u] = w[e]; r[u] = rank[e];
        }
        int o[4];
        #pragma unroll
        for (int u = 0; u < 4; ++u) o[u] = offsets[d[u]];
        #pragma unroll
        for (int u = 0; u < 4; ++u)
            pairs[o[u] + r[u]] = make_int2(s[u], __float_as_int(wv[u]));
    } else {
        #pragma unroll
        for (int u = 0; u < 4; ++u) {
            int e = t + u * 256;
            if (e < E)
                pairs[offsets[dst[e]] + rank[e]] = make_int2(src[e], __float_as_int(w[e]));
        }
    }
}

// deg = 1 + row-sum of w; dis = rsqrt(deg). 16-lane group per node.
__global__ __launch_bounds__(256) void rowsum_dis_kernel(const int* __restrict__ offsets,
                                                         const int2* __restrict__ pairs,
                                                         float* __restrict__ dis, int n) {
    int node = blockIdx.x * 16 + (threadIdx.x >> 4);
    int q = threadIdx.x & 15;
    if (node >= n) return;
    int j0 = offsets[node], end = offsets[node + 1];
    float s = 0.f;
    for (int j = j0 + q; j < end; j += 16) s += __int_as_float(pairs[j].y);
    #pragma unroll
    for (int off = 8; off; off >>= 1) s += __shfl_xor(s, off);
    if (q == 0) dis[node] = rsqrtf(1.0f + s);
}

// g0 = fp16( dis (.) x ); one thread per 8 features
__global__ __launch_bounds__(256) void scale_kernel(const float* __restrict__ x,
                                                    const float* __restrict__ dis,
                                                    __half* __restrict__ g, int n) {
    int i = blockIdx.x * 256 + threadIdx.x;          // 8-float unit index
    if (i >= n * 8) return;
    float d = dis[i >> 3];
    float4 a = reinterpret_cast<const float4*>(x)[i * 2];
    float4 b = reinterpret_cast<const float4*>(x)[i * 2 + 1];
    __half2 h[4];
    h[0] = __float22half2_rn(make_float2(d * a.x, d * a.y));
    h[1] = __float22half2_rn(make_float2(d * a.z, d * a.w));
    h[2] = __float22half2_rn(make_float2(d * b.x, d * b.y));
    h[3] = __float22half2_rn(make_float2(d * b.z, d * b.w));
    reinterpret_cast<float4*>(g)[i] = *reinterpret_cast<float4*>(h);
}

// --------------------------------------- aggregation: agg[d] = dis[d]*(sum w*g[s] + g[d])
// 8-lane group per node (8 nodes/wave); lane q owns half8 #q (features 8q..8q+7).
// One edge gather = one wave VMEM instr moving 8 rows x 128B. fp32 accumulate,
// fp16 output (R7: halves aggregate write + GEMM read).
__device__ __forceinline__ void accum8(float* acc, float4 rv, float w) {
    const __half2* h = reinterpret_cast<const __half2*>(&rv);
    #pragma unroll
    for (int k = 0; k < 4; ++k) {
        float2 f = __half22float2(h[k]);
        acc[2 * k]     = fmaf(w, f.x, acc[2 * k]);
        acc[2 * k + 1] = fmaf(w, f.y, acc[2 * k + 1]);
    }
}

__global__ __launch_bounds__(256) void aggregate_kernel(const __half* __restrict__ g,
                                                        const float* __restrict__ dis,
                                                        const int* __restrict__ offsets,
                                                        const int2* __restrict__ pairs,
                                                        __half* __restrict__ aggout, int n) {
    int node = blockIdx.x * 32 + (threadIdx.x >> 3);
    int q = threadIdx.x & 7;
    if (node >= n) return;
    const float4* gt = reinterpret_cast<const float4*>(g);   // row = 8 x float4 (128B)

    float acc[8] = {0.f, 0.f, 0.f, 0.f, 0.f, 0.f, 0.f, 0.f};
    int j = offsets[node];
    int end = offsets[node + 1];

    for (; j + 4 <= end; j += 4) {
        int2 p0 = pairs[j], p1 = pairs[j + 1], p2 = pairs[j + 2], p3 = pairs[j + 3];
        float4 r0 = gt[(size_t)p0.x * 8 + q];
        float4 r1 = gt[(size_t)p1.x * 8 + q];
        float4 r2 = gt[(size_t)p2.x * 8 + q];
        float4 r3 = gt[(size_t)p3.x * 8 + q];
        accum8(acc, r0, __int_as_float(p0.y));
        accum8(acc, r1, __int_as_float(p1.y));
        accum8(acc, r2, __int_as_float(p2.y));
        accum8(acc, r3, __int_as_float(p3.y));
    }
    for (; j < end; ++j) {
        int2 p = pairs[j];
        float4 r = gt[(size_t)p.x * 8 + q];
        accum8(acc, r, __int_as_float(p.y));
    }

    // self term (weight 1)
    float4 rs = gt[(size_t)node * 8 + q];
    accum8(acc, rs, 1.0f);

    float dn = dis[node];
    __half2 o[4];
    o[0] = __float22half2_rn(make_float2(dn * acc[0], dn * acc[1]));
    o[1] = __float22half2_rn(make_float2(dn * acc[2], dn * acc[3]));
    o[2] = __float22half2_rn(make_float2(dn * acc[4], dn * acc[5]));
    o[3] = __float22half2_rn(make_float2(dn * acc[6], dn * acc[7]));
    reinterpret_cast<float4*>(aggout)[(size_t)node * 8 + q] = *reinterpret_cast<float4*>(o);
}

// ---- helper: load a 64-wide fp16 row into 64 fp32 registers (8x float4 loads)
__device__ __forceinline__ void load_row64(const __half* __restrict__ in, int row,
                                           float* __restrict__ h) {
    const float4* inp = reinterpret_cast<const float4*>(in + (size_t)row * 64);
    #pragma unroll
    for (int i = 0; i < 8; ++i) {
        float4 raw = inp[i];
        const __half2* hp = reinterpret_cast<const __half2*>(&raw);
        #pragma unroll
        for (int k = 0; k < 4; ++k) {
            float2 f = __half22float2(hp[k]);
            h[i * 8 + 2 * k]     = f.x;
            h[i * 8 + 2 * k + 1] = f.y;
        }
    }
}

// ------------------------------------------- GEMM 64x64 + bias + ELU + dis-scale -> fp16
// g_next_row = fp16( dis[row] * elu(in_row @ W + b) )
__global__ __launch_bounds__(256) void gemm64_kernel(const __half* __restrict__ in,
                                                     const float* __restrict__ W,
                                                     const float* __restrict__ b,
                                                     const float* __restrict__ dis,
                                                     __half* __restrict__ out, int n) {
    __shared__ float WT[64][64];   // WT[c][k] = W[k][c]
    for (int idx = threadIdx.x; idx < 64 * 64; idx += 256) {
        int k = idx >> 6, c = idx & 63;
        WT[c][k] = W[idx];
    }
    __syncthreads();

    int row = blockIdx.x * 256 + threadIdx.x;
    if (row >= n) return;

    float h[64];
    load_row64(in, row, h);

    float dn = dis[row];
    __half* outp = out + (size_t)row * 64;
    #pragma unroll 2
    for (int c4 = 0; c4 < 16; ++c4) {
        float4 bv = *reinterpret_cast<const float4*>(b + c4 * 4);
        float r[4];
        #pragma unroll
        for (int cc = 0; cc < 4; ++cc) {
            const float4* wt = reinterpret_cast<const float4*>(&WT[c4 * 4 + cc][0]);
            float4 a = make_float4(0.f, 0.f, 0.f, 0.f);
            #pragma unroll
            for (int i = 0; i < 16; ++i) {
                float4 w4 = wt[i];
                a.x = fmaf(h[4 * i],     w4.x, a.x);
                a.y = fmaf(h[4 * i + 1], w4.y, a.y);
                a.z = fmaf(h[4 * i + 2], w4.z, a.z);
                a.w = fmaf(h[4 * i + 3], w4.w, a.w);
            }
            float v = (a.x + a.y) + (a.z + a.w) + ((const float*)&bv)[cc];
            v = (v > 0.f) ? v : expm1f(v);      // ELU
            r[cc] = dn * v;                     // pre-scale for next aggregate
        }
        __half2 pk[2];
        pk[0] = __float22half2_rn(make_float2(r[0], r[1]));
        pk[1] = __float22half2_rn(make_float2(r[2], r[3]));
        *reinterpret_cast<float2*>(outp + c4 * 4) = *reinterpret_cast<float2*>(pk);
    }
}

// ------------------------------- GEMM 64x40 + bias + fused row log_softmax -> d_out
__global__ __launch_bounds__(256) void gemm40_softmax_kernel(const __half* __restrict__ in,
                                                             const float* __restrict__ W,
                                                             const float* __restrict__ b,
                                                             float* __restrict__ out, int n) {
    __shared__ float WT[40][64];   // WT[c][k] = W[k][c]
    for (int idx = threadIdx.x; idx < 64 * 40; idx += 256) {
        int k = idx / 40, c = idx % 40;
        WT[c][k] = W[idx];
    }
    __syncthreads();

    int row = blockIdx.x * 256 + threadIdx.x;
    if (row >= n) return;

    float h[64];
    load_row64(in, row, h);

    float r[40];
    #pragma unroll 2
    for (int c = 0; c < 40; ++c) {
        const float4* wt = reinterpret_cast<const float4*>(&WT[c][0]);
        float4 a = make_float4(0.f, 0.f, 0.f, 0.f);
        #pragma unroll
        for (int i = 0; i < 16; ++i) {
            float4 w4 = wt[i];
            a.x = fmaf(h[4 * i],     w4.x, a.x);
            a.y = fmaf(h[4 * i + 1], w4.y, a.y);
            a.z = fmaf(h[4 * i + 2], w4.z, a.z);
            a.w = fmaf(h[4 * i + 3], w4.w, a.w);
        }
        r[c] = (a.x + a.y) + (a.z + a.w) + b[c];
    }

    float m = r[0];
    #pragma unroll
    for (int c = 1; c < 40; ++c) m = fmaxf(m, r[c]);
    float s = 0.f;
    #pragma unroll
    for (int c = 0; c < 40; ++c) s += expf(r[c] - m);
    float ls = logf(s) + m;

    float* outp = out + (size_t)row * 40;
    #pragma unroll
    for (int c4 = 0; c4 < 10; ++c4) {
        *reinterpret_cast<float4*>(outp + c4 * 4) =
            make_float4(r[c4 * 4] - ls, r[c4 * 4 + 1] - ls,
                        r[c4 * 4 + 2] - ls, r[c4 * 4 + 3] - ls);
    }
}

// ---------------------------------------------------------------- launch

static inline size_t align_up(size_t x, size_t a) { return (x + a - 1) & ~(a - 1); }

extern "C" void kernel_launch(void* const* d_in, const int* in_sizes, int n_in,
                              void* d_out, int out_size, void* d_ws, size_t ws_size,
                              hipStream_t stream) {
    const float* x  = (const float*)d_in[0];
    const int*   ei = (const int*)d_in[1];     // [2][E] flat: src then dst
    const float* ea = (const float*)d_in[2];
    const float* W1 = (const float*)d_in[3];
    const float* b1 = (const float*)d_in[4];
    const float* W2 = (const float*)d_in[5];
    const float* b2 = (const float*)d_in[6];
    const float* W3 = (const float*)d_in[7];
    const float* b3 = (const float*)d_in[8];
    const float* W4 = (const float*)d_in[9];
    const float* b4 = (const float*)d_in[10];

    const int N = in_sizes[0] / 64;
    const int E = in_sizes[1] / 2;

    const int* src = ei;
    const int* dst = ei + E;

    const int B = (N + 1023) / 1024;

    // workspace carve-up
    char* p = (char*)d_ws;
    int*    cnt     = (int*)p;    p += align_up((size_t)N * 4, 256);
    int*    offsets = (int*)p;    p += align_up(((size_t)N + 1) * 4, 256);
    int*    bsum    = (int*)p;    p += align_up(((size_t)B + 1) * 4, 256);
    float*  dis     = (float*)p;  p += align_up((size_t)N * 4, 256);
    int2*   pairs   = (int2*)p;   p += align_up(((size_t)E + 8) * 8, 256);
    __half* gA      = (__half*)p; p += align_up((size_t)N * 64 * 2, 256);  // fp16 features
    __half* gB      = (__half*)p; p += align_up((size_t)N * 64 * 2, 256);  // fp16 aggregate
    int*    rank    = (int*)gB;   // aliases gB: dead before layer-1 aggregate writes gB
    (void)ws_size;

    const int nb_n   = (N + 255) / 256;
    const int nb_h   = (E + 2047) / 2048;       // hist ILP-8
    const int nb_sc  = (E + 1023) / 1024;       // scatter ILP-4
    const int nb_g16 = (N + 15) / 16;           // 16-lane-group kernels
    const int nb_g8  = (N + 31) / 32;           // 8-lane-group aggregate
    const int nb_s   = ((size_t)N * 8 + 255) / 256;

    // --- graph preprocessing ---
    init_kernel<<<nb_n, 256, 0, stream>>>(cnt, N);
    hist_kernel<<<nb_h, 256, 0, stream>>>(dst, cnt, rank, E);
    scan_block_kernel<<<B, 256, 0, stream>>>(cnt, offsets, bsum, N);
    scan_bsum_kernel<<<1, 64, 0, stream>>>(bsum, B);
    scan_add_kernel<<<B, 256, 0, stream>>>(offsets, bsum, N, E);
    scatter_kernel<<<nb_sc, 256, 0, stream>>>(src, dst, ea, rank, offsets, pairs, E);
    rowsum_dis_kernel<<<nb_g16, 256, 0, stream>>>(offsets, pairs, dis, N);

    // --- g0 = fp16(dis (.) x) ---
    scale_kernel<<<nb_s, 256, 0, stream>>>(x, dis, gA, N);

    // --- layer 1 ---
    aggregate_kernel<<<nb_g8, 256, 0, stream>>>(gA, dis, offsets, pairs, gB, N);
    gemm64_kernel<<<nb_n, 256, 0, stream>>>(gB, W1, b1, dis, gA, N);
    // --- layer 2 ---
    aggregate_kernel<<<nb_g8, 256, 0, stream>>>(gA, dis, offsets, pairs, gB, N);
    gemm64_kernel<<<nb_n, 256, 0, stream>>>(gB, W2, b2, dis, gA, N);
    // --- layer 3 ---
    aggregate_kernel<<<nb_g8, 256, 0, stream>>>(gA, dis, offsets, pairs, gB, N);
    gemm64_kernel<<<nb_n, 256, 0, stream>>>(gB, W3, b3, dis, gA, N);
    // --- layer 4: aggregate then GEMM40 + log_softmax -> d_out ---
    aggregate_kernel<<<nb_g8, 256, 0, stream>>>(gA, dis, offsets, pairs, gB, N);
    gemm40_softmax_kernel<<<nb_n, 256, 0, stream>>>(gB, W4, b4, (float*)d_out, N);
}